// Round 5
// baseline (251.482 us; speedup 1.0000x reference)
//
#include <hip/hip_runtime.h>
#include <stdint.h>

#define NB 4096
#define TT 64
#define CC 128
#define HH 64
#define BPB 4          // batches per block; grid = 1024

typedef __bf16 bf16x8 __attribute__((ext_vector_type(8)));
typedef float f32x4 __attribute__((ext_vector_type(4)));
typedef unsigned short us4 __attribute__((ext_vector_type(4)));

__device__ __forceinline__ unsigned short f2bf(float f) {
  union { float f; uint32_t u; } a; a.f = f;
  uint32_t u = a.u;
  u += 0x7fffu + ((u >> 16) & 1u);   // round-to-nearest-even
  return (unsigned short)(u >> 16);
}

// hardware RNE f32->bf16; same rounding as f2bf
__device__ __forceinline__ unsigned short bfbits(float f) {
  union { __bf16 b; unsigned short u; } c; c.b = (__bf16)f; return c.u;
}

__device__ __forceinline__ bf16x8 cv8(f32x4 lo, f32x4 hi) {
  bf16x8 v;
  #pragma unroll
  for (int j = 0; j < 4; ++j) { v[j] = (__bf16)lo[j]; v[j + 4] = (__bf16)hi[j]; }
  return v;
}

// Pre-swizzle the three [C,H] fp32 weight matrices into MFMA B-fragment order:
// wz[((mat*4 + nt)*4 + ks)*64 + lane][8] = W^T[h = nt*16 + (lane&15)][c = ks*32 + (lane>>4)*8 + j]
__global__ void swizzle_w_kernel(const float* __restrict__ Wq,
                                 const float* __restrict__ Wk,
                                 const float* __restrict__ Wv,
                                 unsigned short* __restrict__ wz) {
  int i = blockIdx.x * 256 + threadIdx.x;   // [0, 3*16*64)
  if (i >= 3 * 16 * 64) return;
  int mat  = i >> 10;
  int rem  = i & 1023;
  int frag = rem >> 6;         // nt*4 + ks
  int lane = rem & 63;
  int nt = frag >> 2, ks = frag & 3;
  int quad = lane >> 4, l15 = lane & 15;
  int h  = nt * 16 + l15;
  int c0 = ks * 32 + quad * 8;
  const float* W = (mat == 0) ? Wq : (mat == 1) ? Wk : Wv;
  unsigned short* o = wz + (size_t)i * 8;
  #pragma unroll
  for (int j = 0; j < 8; ++j) o[j] = f2bf(W[(c0 + j) * HH + h]);
}

#define MFMA16(A, B, C) __builtin_amdgcn_mfma_f32_16x16x32_bf16((A), (B), (C), 0, 0, 0)

// ROUND 0/4 both pinned at 79 us with a 3-barrier-per-batch lockstep (stage x ->
// bar -> proj -> bar -> attn), MfmaUtil 8% / VALUBusy 16% / HBM 21%: pure
// barrier-serialization, not a resource limit. This version: ONE barrier per batch.
//  - x staged NOWHERE: each wave loads its own A-fragments from global (per (mt,ks)
//    pair: 16 rows x 128 B = full-line utilization; the 4x per-block re-read is
//    L2-absorbed since all 4 waves touch the 32 KB tile in one region).
//  - q/k/vT double-buffered (2 x 24 KB): region = proj(b+1)->buf^1 || attn(b)<-buf.
//    Projection's global-load latency hides under attention's MFMA+softmax.
//  - weights: 12 NAMED per-wave register fragments (round-4 lesson: arrays of
//    ext-vectors get scratch-demoted by SROA; named scalars cannot).
__global__ __launch_bounds__(256, 2)
void attn_kernel(const float* __restrict__ x,
                 const unsigned short* __restrict__ wz,
                 float* __restrict__ out) {
  __shared__ unsigned short qbuf[2][64 * 64];  // q rows [t][h]; reused for P
  __shared__ unsigned short kbuf[2][64 * 64];  // k rows [t][h]
  __shared__ unsigned short vbuf[2][64 * 64];  // v transposed [h][t]

  const int tid  = threadIdx.x;
  const int wave = tid >> 6;
  const int lane = tid & 63;
  const int quad = lane >> 4;
  const int l15  = lane & 15;
  const int l7   = l15 & 7;
  const int mbase = wave * 16;
  const float scale = 0.08838834764831845f;  // 128^-0.5 (embed dim, per reference)

  // ---- one-time: this wave's 12 weight B-fragments -> 12 NAMED registers (48 VGPRs)
  const unsigned short* wb = wz + (size_t)lane * 8;
#define WLOAD(P, K) (*(const bf16x8*)(wb + ((size_t)((wave * 3 + (P)) * 4 + (K)) << 9)))
  bf16x8 w00 = WLOAD(0, 0), w01 = WLOAD(0, 1), w02 = WLOAD(0, 2), w03 = WLOAD(0, 3);
  bf16x8 w10 = WLOAD(1, 0), w11 = WLOAD(1, 1), w12 = WLOAD(1, 2), w13 = WLOAD(1, 3);
  bf16x8 w20 = WLOAD(2, 0), w21 = WLOAD(2, 1), w22 = WLOAD(2, 2), w23 = WLOAD(2, 3);
#undef WLOAD

  // ---- one projection column-tile (P in 0..2) for row-tile MT into buffers
#define PROJ1(P, MT, QSB, KSB, VTB) do {                                     \
    f32x4 acc_ = {0.f, 0.f, 0.f, 0.f};                                       \
    acc_ = MFMA16(xf0_, w##P##0, acc_);                                      \
    acc_ = MFMA16(xf1_, w##P##1, acc_);                                      \
    acc_ = MFMA16(xf2_, w##P##2, acc_);                                      \
    acc_ = MFMA16(xf3_, w##P##3, acc_);                                      \
    const int pi_ = wave * 3 + (P);                                          \
    const int mat_ = pi_ >> 2, nt_ = pi_ & 3;                                \
    if (mat_ == 2) {                                                         \
      /* v transposed: 4 consecutive t -> one 8B packed write */             \
      const int h_  = (nt_ << 4) + l15;                                      \
      const int t0_ = ((MT) << 4) + (quad << 2);                             \
      us4 pk_;                                                               \
      pk_[0] = bfbits(acc_[0]); pk_[1] = bfbits(acc_[1]);                    \
      pk_[2] = bfbits(acc_[2]); pk_[3] = bfbits(acc_[3]);                    \
      *(us4*)&(VTB)[(h_ << 6) + (((t0_ >> 3) ^ (h_ & 7)) << 3) + (t0_ & 7)] = pk_; \
    } else {                                                                 \
      unsigned short* dst_ = (mat_ == 0) ? (QSB) : (KSB);                    \
      const int col_ = (nt_ << 4) + l15;                                     \
      const int ch_ = col_ >> 3, cj_ = col_ & 7;                             \
      _Pragma("unroll")                                                      \
      for (int r_ = 0; r_ < 4; ++r_) {                                       \
        const int row_ = ((MT) << 4) + (quad << 2) + r_;                     \
        (dst_)[(row_ << 6) + ((ch_ ^ (row_ & 7)) << 3) + cj_] = bfbits(acc_[r_]); \
      }                                                                      \
    }                                                                        \
  } while (0)

  // ---- full projection of batch BB into (QSB,KSB,VTB); x read straight from global
#define DO_PROJ(BB, QSB, KSB, VTB) do {                                      \
    _Pragma("unroll")                                                        \
    for (int mt_ = 0; mt_ < 4; ++mt_) {                                      \
      const float* xr_ = x + ((size_t)(BB) * TT + mt_ * 16 + l15) * CC + quad * 8; \
      const f32x4 a0_ = *(const f32x4*)(xr_);       const f32x4 b0_ = *(const f32x4*)(xr_ + 4);  \
      const f32x4 a1_ = *(const f32x4*)(xr_ + 32);  const f32x4 b1_ = *(const f32x4*)(xr_ + 36); \
      const f32x4 a2_ = *(const f32x4*)(xr_ + 64);  const f32x4 b2_ = *(const f32x4*)(xr_ + 68); \
      const f32x4 a3_ = *(const f32x4*)(xr_ + 96);  const f32x4 b3_ = *(const f32x4*)(xr_ + 100);\
      const bf16x8 xf0_ = cv8(a0_, b0_), xf1_ = cv8(a1_, b1_);               \
      const bf16x8 xf2_ = cv8(a2_, b2_), xf3_ = cv8(a3_, b3_);               \
      PROJ1(0, mt_, QSB, KSB, VTB);                                          \
      PROJ1(1, mt_, QSB, KSB, VTB);                                          \
      PROJ1(2, mt_, QSB, KSB, VTB);                                          \
    }                                                                        \
  } while (0)

#define QK1(NT, SC, KSB) do {                                                \
    const bf16x8 bk0_ = *(const bf16x8*)&(KSB)[((((NT) << 4) + l15) << 6) + ((quad ^ l7) << 3)]; \
    const bf16x8 bk1_ = *(const bf16x8*)&(KSB)[((((NT) << 4) + l15) << 6) + (((4 + quad) ^ l7) << 3)]; \
    SC = MFMA16(aq0_, bk0_, SC);                                             \
    SC = MFMA16(aq1_, bk1_, SC);                                             \
  } while (0)

#define PV1(NT, QSB, VTB) do {                                               \
    const bf16x8 bv0_ = *(const bf16x8*)&(VTB)[((((NT) << 4) + l15) << 6) + ((quad ^ l7) << 3)]; \
    const bf16x8 bv1_ = *(const bf16x8*)&(VTB)[((((NT) << 4) + l15) << 6) + (((4 + quad) ^ l7) << 3)]; \
    f32x4 acc_ = {0.f, 0.f, 0.f, 0.f};                                       \
    acc_ = MFMA16(ap0_, bv0_, acc_);                                         \
    acc_ = MFMA16(ap1_, bv1_, acc_);                                         \
    _Pragma("unroll")                                                        \
    for (int r_ = 0; r_ < 4; ++r_)                                           \
      ob_[(mbase + (quad << 2) + r_) * HH + ((NT) << 4) + l15] = acc_[r_];   \
  } while (0)

  // ---- attention for batch BB from (QSB,KSB,VTB); this wave's 16 rows
#define DO_ATTN(BB, QSB, KSB, VTB) do {                                      \
    const bf16x8 aq0_ = *(const bf16x8*)&(QSB)[((mbase + l15) << 6) + ((quad ^ l7) << 3)]; \
    const bf16x8 aq1_ = *(const bf16x8*)&(QSB)[((mbase + l15) << 6) + (((4 + quad) ^ l7) << 3)]; \
    f32x4 sc0_ = {0.f, 0.f, 0.f, 0.f}, sc1_ = sc0_, sc2_ = sc0_, sc3_ = sc0_; \
    QK1(0, sc0_, KSB); QK1(1, sc1_, KSB); QK1(2, sc2_, KSB); QK1(3, sc3_, KSB); \
    _Pragma("unroll")                                                        \
    for (int r_ = 0; r_ < 4; ++r_) {                                         \
      const int row_ = mbase + (quad << 2) + r_;                             \
      float v0_ = (l15      <= row_) ? sc0_[r_] * scale : -__builtin_inff(); \
      float v1_ = (l15 + 16 <= row_) ? sc1_[r_] * scale : -__builtin_inff(); \
      float v2_ = (l15 + 32 <= row_) ? sc2_[r_] * scale : -__builtin_inff(); \
      float v3_ = (l15 + 48 <= row_) ? sc3_[r_] * scale : -__builtin_inff(); \
      float m_ = fmaxf(fmaxf(v0_, v1_), fmaxf(v2_, v3_));                    \
      _Pragma("unroll")                                                      \
      for (int d_ = 1; d_ < 16; d_ <<= 1) m_ = fmaxf(m_, __shfl_xor(m_, d_, 64)); \
      v0_ = __expf(v0_ - m_); v1_ = __expf(v1_ - m_);                        \
      v2_ = __expf(v2_ - m_); v3_ = __expf(v3_ - m_);                        \
      float s_ = (v0_ + v1_) + (v2_ + v3_);                                  \
      _Pragma("unroll")                                                      \
      for (int d_ = 1; d_ < 16; d_ <<= 1) s_ += __shfl_xor(s_, d_, 64);      \
      const float inv_ = 1.f / s_;                                           \
      const int rs_ = row_ & 7;                                              \
      /* P overwrites this wave's own q rows (wave-private) -> no barrier */ \
      (QSB)[(row_ << 6) + ((( (l15 >> 3)    ) ^ rs_) << 3) + (l15 & 7)] = bfbits(v0_ * inv_); \
      (QSB)[(row_ << 6) + ((((l15 >> 3) + 2) ^ rs_) << 3) + (l15 & 7)] = bfbits(v1_ * inv_); \
      (QSB)[(row_ << 6) + ((((l15 >> 3) + 4) ^ rs_) << 3) + (l15 & 7)] = bfbits(v2_ * inv_); \
      (QSB)[(row_ << 6) + ((((l15 >> 3) + 6) ^ rs_) << 3) + (l15 & 7)] = bfbits(v3_ * inv_); \
    }                                                                        \
    const bf16x8 ap0_ = *(const bf16x8*)&(QSB)[((mbase + l15) << 6) + ((quad ^ l7) << 3)]; \
    const bf16x8 ap1_ = *(const bf16x8*)&(QSB)[((mbase + l15) << 6) + (((4 + quad) ^ l7) << 3)]; \
    float* ob_ = out + (size_t)(BB) * TT * HH;                               \
    PV1(0, QSB, VTB); PV1(1, QSB, VTB); PV1(2, QSB, VTB); PV1(3, QSB, VTB);  \
  } while (0)

  const int b0 = blockIdx.x * BPB;

  // prologue: project batch b0 into buffer 0
  DO_PROJ(b0, qbuf[0], kbuf[0], vbuf[0]);
  __syncthreads();

  #pragma unroll
  for (int bi = 0; bi < BPB; ++bi) {
    const int cu_ = bi & 1;                 // compile-time (loop unrolled)
    // proj(b+1) -> alternate buffer: global x loads overlap attn(b)'s compute
    if (bi < BPB - 1) DO_PROJ(b0 + bi + 1, qbuf[cu_ ^ 1], kbuf[cu_ ^ 1], vbuf[cu_ ^ 1]);
    DO_ATTN(b0 + bi, qbuf[cu_], kbuf[cu_], vbuf[cu_]);
    __syncthreads();                        // ONE barrier per batch
  }
}

extern "C" void kernel_launch(void* const* d_in, const int* in_sizes, int n_in,
                              void* d_out, int out_size, void* d_ws, size_t ws_size,
                              hipStream_t stream) {
  const float* x  = (const float*)d_in[0];
  const float* Wq = (const float*)d_in[1];
  const float* Wk = (const float*)d_in[2];
  const float* Wv = (const float*)d_in[3];
  unsigned short* wz = (unsigned short*)d_ws;   // 3*16*64*8 bf16 = 48 KiB scratch
  float* outp = (float*)d_out;

  swizzle_w_kernel<<<(3 * 16 * 64 + 255) / 256, 256, 0, stream>>>(Wq, Wk, Wv, wz);
  attn_kernel<<<NB / BPB, 256, 0, stream>>>(x, wz, outp);
}

// Round 6
// 235.961 us; speedup vs baseline: 1.0658x; 1.0658x over previous
//
#include <hip/hip_runtime.h>
#include <stdint.h>

#define NB 4096
#define TT 64
#define CC 128
#define HH 64

typedef __bf16 bf16x8 __attribute__((ext_vector_type(8)));
typedef float f32x4 __attribute__((ext_vector_type(4)));
typedef unsigned short us4 __attribute__((ext_vector_type(4)));

__device__ __forceinline__ unsigned short f2bf(float f) {
  union { float f; uint32_t u; } a; a.f = f;
  uint32_t u = a.u;
  u += 0x7fffu + ((u >> 16) & 1u);   // round-to-nearest-even
  return (unsigned short)(u >> 16);
}

// hardware RNE f32->bf16; same rounding as f2bf
__device__ __forceinline__ unsigned short bfbits(float f) {
  union { __bf16 b; unsigned short u; } c; c.b = (__bf16)f; return c.u;
}

__device__ __forceinline__ bf16x8 cv8(f32x4 lo, f32x4 hi) {
  bf16x8 v;
  #pragma unroll
  for (int j = 0; j < 4; ++j) { v[j] = (__bf16)lo[j]; v[j + 4] = (__bf16)hi[j]; }
  return v;
}

// Pre-swizzle the three [C,H] fp32 weight matrices into MFMA B-fragment order:
// wz[((mat*4 + nt)*4 + ks)*64 + lane][8] = W^T[h = nt*16 + (lane&15)][c = ks*32 + (lane>>4)*8 + j]
__global__ void swizzle_w_kernel(const float* __restrict__ Wq,
                                 const float* __restrict__ Wk,
                                 const float* __restrict__ Wv,
                                 unsigned short* __restrict__ wz) {
  int i = blockIdx.x * 256 + threadIdx.x;   // [0, 3*16*64)
  if (i >= 3 * 16 * 64) return;
  int mat  = i >> 10;
  int rem  = i & 1023;
  int frag = rem >> 6;         // nt*4 + ks
  int lane = rem & 63;
  int nt = frag >> 2, ks = frag & 3;
  int quad = lane >> 4, l15 = lane & 15;
  int h  = nt * 16 + l15;
  int c0 = ks * 32 + quad * 8;
  const float* W = (mat == 0) ? Wq : (mat == 1) ? Wk : Wv;
  unsigned short* o = wz + (size_t)i * 8;
  #pragma unroll
  for (int j = 0; j < 8; ++j) o[j] = f2bf(W[(c0 + j) * HH + h]);
}

#define MFMA16(A, B, C) __builtin_amdgcn_mfma_f32_16x16x32_bf16((A), (B), (C), 0, 0, 0)

// Swizzled b128 LDS read: 16B chunk CH of row ROW (chunk index XOR'd with row&7)
#define LDB(BUF, ROW, CH) (*(const bf16x8*)&(BUF)[((ROW) << 6) + (((CH) ^ ((ROW) & 7)) << 3)])

// ROUNDS 0-5 POST-MORTEM: three different 4-wave barrier-lockstep structures all
// floor at 79-100 us with ~75% stall and 17-24% achieved occupancy; total issue
// work is only ~3 us. The invariant is the block-wide barrier choreography.
// THIS VERSION: one wave owns one whole batch. No __syncthreads anywhere.
//  - transposes via wave-PRIVATE 16 KB LDS (bufA: Q then P; bufB: K then V^T,
//    sequentially reused; within-wave RAW ordering is just lgkmcnt).
//  - weights streamed from the global 48 KB frag table (L2-resident) per matrix,
//    16 x 1KB coalesced frag loads, all individually NAMED (r4 lesson: any
//    ext-vector array with loop-var indexing gets scratch-demoted by SROA).
//  - grid 4096 one-wave blocks -> ~10 independent waves/CU; latency hidden by
//    TLP across unsynchronized waves instead of intra-block phase choreography.
__global__ __launch_bounds__(64, 2)
void attn_kernel(const float* __restrict__ x,
                 const unsigned short* __restrict__ wz,
                 float* __restrict__ out) {
  __shared__ unsigned short bufA[64 * 64];   // Q rows [t][h], then P rows [t][s]
  __shared__ unsigned short bufB[64 * 64];   // K rows [s][h], then V^T [h][t]

  const int lane = threadIdx.x & 63;
  const int quad = lane >> 4;
  const int l15  = lane & 15;
  const float scale = 0.08838834764831845f;  // 128^-0.5 (embed dim, per reference)
  const int b = blockIdx.x;
  const unsigned short* wb = wz + (size_t)lane * 8;

  // ---- x tile -> 16 named A-fragments: xf{mt}{ks} = x[16mt+l15][32ks+8quad+j]
#define XFRAG(MT) \
  bf16x8 xf##MT##0, xf##MT##1, xf##MT##2, xf##MT##3; \
  { const float* xr_ = x + ((size_t)b * TT + (MT) * 16 + l15) * CC + (quad << 3); \
    const f32x4 p0_ = *(const f32x4*)(xr_);      const f32x4 q0_ = *(const f32x4*)(xr_ + 4);   \
    const f32x4 p1_ = *(const f32x4*)(xr_ + 32); const f32x4 q1_ = *(const f32x4*)(xr_ + 36);  \
    const f32x4 p2_ = *(const f32x4*)(xr_ + 64); const f32x4 q2_ = *(const f32x4*)(xr_ + 68);  \
    const f32x4 p3_ = *(const f32x4*)(xr_ + 96); const f32x4 q3_ = *(const f32x4*)(xr_ + 100); \
    xf##MT##0 = cv8(p0_, q0_); xf##MT##1 = cv8(p1_, q1_); \
    xf##MT##2 = cv8(p2_, q2_); xf##MT##3 = cv8(p3_, q3_); }
  XFRAG(0) XFRAG(1) XFRAG(2) XFRAG(3)
#undef XFRAG

  // weight B-fragment (mat M, col-tile NT, k-slice KS) from global table (L2-hit)
#define WL(M, NT, KS) (*(const bf16x8*)(wb + (((size_t)(M) * 16 + (NT) * 4 + (KS)) << 9)))

  // row-major swizzled store of a proj acc: rows 16MT+4quad+r, col 16NT+l15
#define WRROW(BUF, MT, NT, ACC) do { \
    const int h_ = ((NT) << 4) + l15; \
    const int ch_ = h_ >> 3, cj_ = h_ & 7; \
    _Pragma("unroll") \
    for (int r_ = 0; r_ < 4; ++r_) { \
      const int t_ = ((MT) << 4) + (quad << 2) + r_; \
      (BUF)[(t_ << 6) + ((ch_ ^ (t_ & 7)) << 3) + cj_] = bfbits(ACC[r_]); \
    } } while (0)

  // transposed [h][t] store: 4 consecutive t at fixed h -> one 8B packed write
#define WRVT(BUF, MT, NT, ACC) do { \
    const int h_  = ((NT) << 4) + l15; \
    const int t0_ = ((MT) << 4) + (quad << 2); \
    us4 pk_; pk_[0] = bfbits(ACC[0]); pk_[1] = bfbits(ACC[1]); \
    pk_[2] = bfbits(ACC[2]); pk_[3] = bfbits(ACC[3]); \
    *(us4*)&(BUF)[(h_ << 6) + (((t0_ >> 3) ^ (h_ & 7)) << 3) + (t0_ & 7)] = pk_; \
  } while (0)

#define PTILE(MT, NT, WRM, BUF) { \
    f32x4 acc_ = {0.f, 0.f, 0.f, 0.f}; \
    acc_ = MFMA16(xf##MT##0, w##NT##0_, acc_); \
    acc_ = MFMA16(xf##MT##1, w##NT##1_, acc_); \
    acc_ = MFMA16(xf##MT##2, w##NT##2_, acc_); \
    acc_ = MFMA16(xf##MT##3, w##NT##3_, acc_); \
    WRM(BUF, MT, NT, acc_); }

  // full 64x64 projection of mat M into BUF (16 named w frags, 16 tiles)
#define PROJ(M, WRM, BUF) do { \
    const bf16x8 w00_ = WL(M,0,0), w01_ = WL(M,0,1), w02_ = WL(M,0,2), w03_ = WL(M,0,3); \
    const bf16x8 w10_ = WL(M,1,0), w11_ = WL(M,1,1), w12_ = WL(M,1,2), w13_ = WL(M,1,3); \
    const bf16x8 w20_ = WL(M,2,0), w21_ = WL(M,2,1), w22_ = WL(M,2,2), w23_ = WL(M,2,3); \
    const bf16x8 w30_ = WL(M,3,0), w31_ = WL(M,3,1), w32_ = WL(M,3,2), w33_ = WL(M,3,3); \
    PTILE(0,0,WRM,BUF) PTILE(0,1,WRM,BUF) PTILE(0,2,WRM,BUF) PTILE(0,3,WRM,BUF) \
    PTILE(1,0,WRM,BUF) PTILE(1,1,WRM,BUF) PTILE(1,2,WRM,BUF) PTILE(1,3,WRM,BUF) \
    PTILE(2,0,WRM,BUF) PTILE(2,1,WRM,BUF) PTILE(2,2,WRM,BUF) PTILE(2,3,WRM,BUF) \
    PTILE(3,0,WRM,BUF) PTILE(3,1,WRM,BUF) PTILE(3,2,WRM,BUF) PTILE(3,3,WRM,BUF) \
  } while (0)

  PROJ(0, WRROW, bufA);   // Q -> bufA
  PROJ(1, WRROW, bufB);   // K -> bufB

  // ---- K B-fragments into registers (bufB is reused for V^T afterwards)
  const bf16x8 kb00 = LDB(bufB,      l15, quad), kb01 = LDB(bufB,      l15, 4 + quad);
  const bf16x8 kb10 = LDB(bufB, 16 + l15, quad), kb11 = LDB(bufB, 16 + l15, 4 + quad);
  const bf16x8 kb20 = LDB(bufB, 32 + l15, quad), kb21 = LDB(bufB, 32 + l15, 4 + quad);
  const bf16x8 kb30 = LDB(bufB, 48 + l15, quad), kb31 = LDB(bufB, 48 + l15, 4 + quad);

  // ---- QK^T + softmax, one 16-row tile at a time; P overwrites Q rows in bufA
#define QKMT(MT) do { \
    const int tb_ = (MT) << 4; \
    const bf16x8 qa0_ = LDB(bufA, tb_ + l15, quad); \
    const bf16x8 qa1_ = LDB(bufA, tb_ + l15, 4 + quad); \
    f32x4 s0_ = {0.f, 0.f, 0.f, 0.f}, s1_ = s0_, s2_ = s0_, s3_ = s0_; \
    s0_ = MFMA16(qa0_, kb00, s0_); s0_ = MFMA16(qa1_, kb01, s0_); \
    s1_ = MFMA16(qa0_, kb10, s1_); s1_ = MFMA16(qa1_, kb11, s1_); \
    s2_ = MFMA16(qa0_, kb20, s2_); s2_ = MFMA16(qa1_, kb21, s2_); \
    s3_ = MFMA16(qa0_, kb30, s3_); s3_ = MFMA16(qa1_, kb31, s3_); \
    _Pragma("unroll") \
    for (int r_ = 0; r_ < 4; ++r_) { \
      const int row_ = tb_ + (quad << 2) + r_; \
      float v0_ = (l15      <= row_) ? s0_[r_] * scale : -__builtin_inff(); \
      float v1_ = (l15 + 16 <= row_) ? s1_[r_] * scale : -__builtin_inff(); \
      float v2_ = (l15 + 32 <= row_) ? s2_[r_] * scale : -__builtin_inff(); \
      float v3_ = (l15 + 48 <= row_) ? s3_[r_] * scale : -__builtin_inff(); \
      float m_ = fmaxf(fmaxf(v0_, v1_), fmaxf(v2_, v3_)); \
      _Pragma("unroll") \
      for (int d_ = 1; d_ < 16; d_ <<= 1) m_ = fmaxf(m_, __shfl_xor(m_, d_, 64)); \
      v0_ = __expf(v0_ - m_); v1_ = __expf(v1_ - m_); \
      v2_ = __expf(v2_ - m_); v3_ = __expf(v3_ - m_); \
      float sm_ = (v0_ + v1_) + (v2_ + v3_); \
      _Pragma("unroll") \
      for (int d_ = 1; d_ < 16; d_ <<= 1) sm_ += __shfl_xor(sm_, d_, 64); \
      const float inv_ = 1.f / sm_; \
      const int rs_ = row_ & 7; \
      const int base_ = (row_ << 6) + (l15 & 7); \
      const int lh_ = l15 >> 3; \
      bufA[base_ + (((lh_    ) ^ rs_) << 3)] = bfbits(v0_ * inv_); \
      bufA[base_ + (((lh_ + 2) ^ rs_) << 3)] = bfbits(v1_ * inv_); \
      bufA[base_ + (((lh_ + 4) ^ rs_) << 3)] = bfbits(v2_ * inv_); \
      bufA[base_ + (((lh_ + 6) ^ rs_) << 3)] = bfbits(v3_ * inv_); \
    } } while (0)

  QKMT(0); QKMT(1); QKMT(2); QKMT(3);

  PROJ(2, WRVT, bufB);    // V^T -> bufB (K already consumed into kb registers)

  // ---- V^T B-fragments
  const bf16x8 vb00 = LDB(bufB,      l15, quad), vb01 = LDB(bufB,      l15, 4 + quad);
  const bf16x8 vb10 = LDB(bufB, 16 + l15, quad), vb11 = LDB(bufB, 16 + l15, 4 + quad);
  const bf16x8 vb20 = LDB(bufB, 32 + l15, quad), vb21 = LDB(bufB, 32 + l15, 4 + quad);
  const bf16x8 vb30 = LDB(bufB, 48 + l15, quad), vb31 = LDB(bufB, 48 + l15, 4 + quad);

  // ---- O = P @ V, one 16-row tile at a time; fp32 stores
#define PVMT(MT) do { \
    const int tb_ = (MT) << 4; \
    const bf16x8 pa0_ = LDB(bufA, tb_ + l15, quad); \
    const bf16x8 pa1_ = LDB(bufA, tb_ + l15, 4 + quad); \
    f32x4 o0_ = {0.f, 0.f, 0.f, 0.f}, o1_ = o0_, o2_ = o0_, o3_ = o0_; \
    o0_ = MFMA16(pa0_, vb00, o0_); o0_ = MFMA16(pa1_, vb01, o0_); \
    o1_ = MFMA16(pa0_, vb10, o1_); o1_ = MFMA16(pa1_, vb11, o1_); \
    o2_ = MFMA16(pa0_, vb20, o2_); o2_ = MFMA16(pa1_, vb21, o2_); \
    o3_ = MFMA16(pa0_, vb30, o3_); o3_ = MFMA16(pa1_, vb31, o3_); \
    float* ob_ = out + ((size_t)b * TT + tb_ + (quad << 2)) * HH + l15; \
    _Pragma("unroll") \
    for (int r_ = 0; r_ < 4; ++r_) { \
      ob_[r_ * HH     ] = o0_[r_]; \
      ob_[r_ * HH + 16] = o1_[r_]; \
      ob_[r_ * HH + 32] = o2_[r_]; \
      ob_[r_ * HH + 48] = o3_[r_]; \
    } } while (0)

  PVMT(0); PVMT(1); PVMT(2); PVMT(3);
}

extern "C" void kernel_launch(void* const* d_in, const int* in_sizes, int n_in,
                              void* d_out, int out_size, void* d_ws, size_t ws_size,
                              hipStream_t stream) {
  const float* x  = (const float*)d_in[0];
  const float* Wq = (const float*)d_in[1];
  const float* Wk = (const float*)d_in[2];
  const float* Wv = (const float*)d_in[3];
  unsigned short* wz = (unsigned short*)d_ws;   // 3*16*64*8 bf16 = 48 KiB scratch
  float* outp = (float*)d_out;

  swizzle_w_kernel<<<(3 * 16 * 64 + 255) / 256, 256, 0, stream>>>(Wq, Wk, Wv, wz);
  attn_kernel<<<NB, 64, 0, stream>>>(x, wz, outp);
}